// Round 1
// baseline (413.925 us; speedup 1.0000x reference)
//
#include <hip/hip_runtime.h>
#include <cstdint>
#include <cstddef>

// ---------------------------------------------------------------------------
// MultiHeadAttentionQuantum: out = cos(x @ Wp^T + phi) @ Wc^T
//   x: [32768, 1024] fp32, Wp/Wc: [1024, 1024] fp32 (row f = output feature),
//   phi: [256,4] -> flat [1024] fp32. out: [32768, 1024] fp32.
// Strategy: bf16 MFMA (16x16x32), m97-style 128x128 tile GEMM with
// global_load_lds width-16 staging; cos fused into GEMM1 epilogue.
// ---------------------------------------------------------------------------

typedef __attribute__((ext_vector_type(8))) short short8;
typedef __attribute__((ext_vector_type(4))) float f32x4;

__device__ __forceinline__ unsigned short f2bf(float f) {
  unsigned u = __float_as_uint(f);
  u += 0x7FFFu + ((u >> 16) & 1u);   // RNE
  return (unsigned short)(u >> 16);
}

__device__ __forceinline__ void async_load16(const void* g, const void* l) {
  __builtin_amdgcn_global_load_lds(
      (const __attribute__((address_space(1))) void*)g,
      (__attribute__((address_space(3))) void*)l,
      16, 0, 0);
}

// --------------------------- fp32 -> bf16 cast -----------------------------
__global__ __launch_bounds__(256) void cast_f32_bf16(
    const float* __restrict__ src, unsigned short* __restrict__ dst, int n) {
  int i = (blockIdx.x * 256 + threadIdx.x) * 4;
  if (i >= n) return;
  const float4 v = *(const float4*)(src + i);
  ushort4 o;
  o.x = f2bf(v.x);
  o.y = f2bf(v.y);
  o.z = f2bf(v.z);
  o.w = f2bf(v.w);
  *(ushort4*)(dst + i) = o;
}

// ------------------------------- GEMM ---------------------------------------
// C[m, n] = sum_k A[m, k] * B[n, k]   (B stored row-major [N, K], i.e. B^T GEMM)
// EPI==1: store bf16 cos(acc + phi[n]) to Cout (unsigned short*)
// EPI==0: store fp32 acc to Cout (float*)
constexpr int TM = 128, TN = 128, BK = 32;
constexpr int Kdim = 1024, Ndim = 1024;

template <int EPI>
__global__ __launch_bounds__(256, 2) void gemm_bt(
    const unsigned short* __restrict__ A,   // [M, 1024] bf16
    const unsigned short* __restrict__ B,   // [1024, 1024] bf16
    const float* __restrict__ phi,          // [1024] fp32 (EPI==1 only)
    void* __restrict__ Cout) {
  __shared__ unsigned short As[TM * BK];    // 8 KB
  __shared__ unsigned short Bs[TN * BK];    // 8 KB

  const int tid  = threadIdx.x;
  const int lane = tid & 63;
  const int wv   = tid >> 6;                // 0..3
  const int m_blk = blockIdx.x >> 3;        // 256 row blocks
  const int n_blk = blockIdx.x & 7;         // 8 col blocks
  const long row0 = (long)m_blk * TM;
  const int  col0 = n_blk * TN;

  // staging geometry: chunk = 16 rows (1024 B); lane covers row=chunk*16+lane/4,
  // byte col (lane&3)*16. LDS dest = wave-uniform base + lane*16 (HW rule).
  const int s_row  = lane >> 2;
  const int s_colb = (lane & 3) * 16;

  const int lane15 = lane & 15;
  const int quad   = lane >> 4;
  const int wm = (wv >> 1) * 64;            // wave's 64x64 quadrant
  const int wn = (wv & 1) * 64;

  f32x4 acc[4][4];
#pragma unroll
  for (int mi = 0; mi < 4; ++mi)
#pragma unroll
    for (int ni = 0; ni < 4; ++ni) {
      f32x4 z = {0.f, 0.f, 0.f, 0.f};
      acc[mi][ni] = z;
    }

  for (int k0 = 0; k0 < Kdim; k0 += BK) {
#pragma unroll
    for (int j = 0; j < 2; ++j) {
      const int chunk = wv * 2 + j;              // 0..7
      const int row = chunk * 16 + s_row;        // 0..127
      const char* ga = (const char*)(A + (row0 + row) * Kdim + k0) + s_colb;
      async_load16(ga, (const char*)As + chunk * 1024);
      const char* gb = (const char*)(B + (long)(col0 + row) * Kdim + k0) + s_colb;
      async_load16(gb, (const char*)Bs + chunk * 1024);
    }
    __syncthreads();   // compiler emits s_waitcnt vmcnt(0) before s_barrier

    short8 af[4], bfr[4];
#pragma unroll
    for (int mi = 0; mi < 4; ++mi)
      af[mi] = *(const short8*)(As + (wm + mi * 16 + lane15) * BK + quad * 8);
#pragma unroll
    for (int ni = 0; ni < 4; ++ni)
      bfr[ni] = *(const short8*)(Bs + (wn + ni * 16 + lane15) * BK + quad * 8);
#pragma unroll
    for (int mi = 0; mi < 4; ++mi)
#pragma unroll
      for (int ni = 0; ni < 4; ++ni)
        acc[mi][ni] = __builtin_amdgcn_mfma_f32_16x16x32_bf16(
            af[mi], bfr[ni], acc[mi][ni], 0, 0, 0);
    __syncthreads();
  }

  // Epilogue. C/D layout (m89-verified): col = lane&15, row = quad*4 + reg.
  if (EPI == 1) {
    unsigned short* Q = (unsigned short*)Cout;
    float ph[4];
#pragma unroll
    for (int ni = 0; ni < 4; ++ni)
      ph[ni] = phi[col0 + wn + ni * 16 + lane15];
#pragma unroll
    for (int mi = 0; mi < 4; ++mi) {
      const long rbase = row0 + wm + mi * 16 + quad * 4;
#pragma unroll
      for (int ni = 0; ni < 4; ++ni) {
        const int c = col0 + wn + ni * 16 + lane15;
#pragma unroll
        for (int r = 0; r < 4; ++r) {
          float v = __cosf(acc[mi][ni][r] + ph[ni]);
          Q[(rbase + r) * Ndim + c] = f2bf(v);
        }
      }
    }
  } else {
    float* C = (float*)Cout;
#pragma unroll
    for (int mi = 0; mi < 4; ++mi) {
      const long rbase = row0 + wm + mi * 16 + quad * 4;
#pragma unroll
      for (int ni = 0; ni < 4; ++ni) {
        const int c = col0 + wn + ni * 16 + lane15;
#pragma unroll
        for (int r = 0; r < 4; ++r)
          C[(rbase + r) * Ndim + c] = acc[mi][ni][r];
      }
    }
  }
}

// ------------------------------- launch -------------------------------------
extern "C" void kernel_launch(void* const* d_in, const int* in_sizes, int n_in,
                              void* d_out, int out_size, void* d_ws, size_t ws_size,
                              hipStream_t stream) {
  const float* x   = (const float*)d_in[0];   // 8*4096*1024 = 33554432
  const float* Wp  = (const float*)d_in[1];   // 1048576
  const float* Wc  = (const float*)d_in[2];   // 1048576
  const float* phi = (const float*)d_in[3];   // 1024
  float* out = (float*)d_out;

  // workspace layout (bytes):
  //   Abf  @ 0         : 67108864  (32768x1024 bf16)
  //   Qbf  @ 67108864  : 67108864  (32768x1024 bf16)
  //   Wpbf @ 134217728 : 2097152
  //   Wcbf @ 136314880 : 2097152   -> total 138412032 B
  char* ws = (char*)d_ws;
  unsigned short* Abf  = (unsigned short*)(ws);
  unsigned short* Qbf  = (unsigned short*)(ws + (size_t)67108864);
  unsigned short* Wpbf = (unsigned short*)(ws + (size_t)134217728);
  unsigned short* Wcbf = (unsigned short*)(ws + (size_t)136314880);

  cast_f32_bf16<<<32768, 256, 0, stream>>>(x, Abf, 33554432);
  cast_f32_bf16<<<1024, 256, 0, stream>>>(Wp, Wpbf, 1048576);
  cast_f32_bf16<<<1024, 256, 0, stream>>>(Wc, Wcbf, 1048576);

  // grid: 256 m-blocks x 8 n-blocks; consecutive blocks share A rows (L2)
  gemm_bt<1><<<2048, 256, 0, stream>>>(Abf, Wpbf, phi, (void*)Qbf);
  gemm_bt<0><<<2048, 256, 0, stream>>>(Qbf, Wcbf, nullptr, (void*)out);

  (void)in_sizes; (void)n_in; (void)out_size; (void)ws_size;
}